// Round 1
// baseline (582.917 us; speedup 1.0000x reference)
//
#include <hip/hip_runtime.h>

// GCN 2-layer fused:  out = relu( A·(A·x)·(W1@W2) + (A·1)⊗(b1ᵀW2) + b2 )
// A = D^-1/2 (Adj + I) D^-1/2, D = in-degree (dst-side) incl. self-loop.

#define WS_ALIGN(x) (((x) + 255) & ~(size_t)255)

__global__ void k_init_deg(int* __restrict__ deg, int N) {
    int i = blockIdx.x * blockDim.x + threadIdx.x;
    if (i < N) deg[i] = 1;   // self-loop
}

__global__ void k_degree(const int* __restrict__ dst, int* __restrict__ deg, int E, int N) {
    int e = blockIdx.x * blockDim.x + threadIdx.x;
    if (e < E) {
        int d = dst[e];
        if ((unsigned)d < (unsigned)N) atomicAdd(&deg[d], 1);
    }
}

__global__ void k_dinv(const int* __restrict__ deg, float* __restrict__ dinv, int N) {
    int i = blockIdx.x * blockDim.x + threadIdx.x;
    if (i < N) dinv[i] = rsqrtf((float)deg[i]);
}

// Block-local exclusive scan of indeg = deg-1 (256/block), emits block sums.
__global__ void k_scan1(const int* __restrict__ deg, int* __restrict__ offs,
                        int* __restrict__ bsums, int N) {
    __shared__ int sh[256];
    int i = blockIdx.x * 256 + threadIdx.x;
    int v = (i < N) ? (deg[i] - 1) : 0;
    sh[threadIdx.x] = v;
    __syncthreads();
    for (int off = 1; off < 256; off <<= 1) {
        int t = (threadIdx.x >= off) ? sh[threadIdx.x - off] : 0;
        __syncthreads();
        sh[threadIdx.x] += t;
        __syncthreads();
    }
    if (i < N) offs[i] = sh[threadIdx.x] - v;
    if (threadIdx.x == 255) bsums[blockIdx.x] = sh[255];
}

// Exclusive scan of up to 512 block sums in one block.
__global__ void k_scan2(int* __restrict__ bsums, int nb) {
    __shared__ int sh[512];
    int tid = threadIdx.x;
    int v = (tid < nb) ? bsums[tid] : 0;
    sh[tid] = v;
    __syncthreads();
    for (int off = 1; off < 512; off <<= 1) {
        int t = (tid >= off) ? sh[tid - off] : 0;
        __syncthreads();
        sh[tid] += t;
        __syncthreads();
    }
    if (tid < nb) bsums[tid] = sh[tid] - v;
}

__global__ void k_scan3(int* __restrict__ offs, const int* __restrict__ bsums,
                        int* __restrict__ cursor, int N, int E) {
    int i = blockIdx.x * 256 + threadIdx.x;
    if (i < N) {
        int o = offs[i] + bsums[blockIdx.x];
        offs[i] = o;
        cursor[i] = o;
    }
    if (blockIdx.x == 0 && threadIdx.x == 0) offs[N] = E;
}

__global__ void k_fill(const int* __restrict__ src, const int* __restrict__ dst,
                       int* __restrict__ cursor, int* __restrict__ csr, int E, int N) {
    int e = blockIdx.x * blockDim.x + threadIdx.x;
    if (e < E) {
        int d = dst[e];
        int s = src[e];
        if ((unsigned)d < (unsigned)N && (unsigned)s < (unsigned)N) {
            int pos = atomicAdd(&cursor[d], 1);
            csr[pos] = s;
        }
    }
}

// Pull aggregation: out[i] = dinv[i] * ( dinv[i]*x[i] + sum_{s in in(i)} dinv[s]*x[s] )
// One 64-lane wave per node, each lane owns 2 features (float2 = 512B/row/wave).
template <int WITH_S>
__global__ void k_agg(const float* __restrict__ xin, float* __restrict__ xout,
                      const int* __restrict__ offs, const int* __restrict__ csr,
                      const float* __restrict__ dinv, float* __restrict__ svec, int N) {
    int gw = (int)((blockIdx.x * (size_t)blockDim.x + threadIdx.x) >> 6);
    int lane = threadIdx.x & 63;
    if (gw >= N) return;
    float di = dinv[gw];
    const float2* x2 = (const float2*)xin;
    float2 acc = x2[(size_t)gw * 64 + lane];
    acc.x *= di;
    acc.y *= di;
    float ssum = di;  // self term of sum dinv[s]
    int s0 = offs[gw], s1 = offs[gw + 1];
    for (int base = s0; base < s1; base += 64) {
        int cnt = min(64, s1 - base);
        int sidx = 0;
        float dv = 0.f;
        if (lane < cnt) {
            sidx = csr[base + lane];
            dv = dinv[sidx];
        }
#pragma unroll 4
        for (int t = 0; t < cnt; ++t) {
            int s = __shfl(sidx, t);
            float d = __shfl(dv, t);
            float2 v = x2[(size_t)s * 64 + lane];
            acc.x = fmaf(d, v.x, acc.x);
            acc.y = fmaf(d, v.y, acc.y);
            if (WITH_S) ssum += d;
        }
    }
    acc.x *= di;
    acc.y *= di;
    ((float2*)xout)[(size_t)gw * 64 + lane] = acc;
    if (WITH_S && lane == 0) svec[gw] = di * ssum;
}

// W12 = W1 @ W2  (128x128 @ 128x128), one output per thread.
__global__ void k_w12(const float* __restrict__ W1, const float* __restrict__ W2,
                      float* __restrict__ w12) {
    int idx = blockIdx.x * 256 + threadIdx.x;  // 0..16383
    int i = idx >> 7, j = idx & 127;
    float s = 0.f;
#pragma unroll 8
    for (int k = 0; k < 128; ++k) s = fmaf(W1[i * 128 + k], W2[k * 128 + j], s);
    w12[idx] = s;
}

// cvec = b1^T @ W2  (128,)
__global__ void k_cvec(const float* __restrict__ b1, const float* __restrict__ W2,
                       float* __restrict__ cvec) {
    int j = threadIdx.x;
    float s = 0.f;
#pragma unroll 8
    for (int k = 0; k < 128; ++k) s = fmaf(b1[k], W2[k * 128 + j], s);
    cvec[j] = s;
}

// out = relu( X @ W12 + svec ⊗ cvec + b2 )  — fp32 vector GEMM, LDS-tiled.
// Block: 256 threads, 64 rows. W12 (64KB) + x tile (32KB, XOR-swizzled) in LDS.
__launch_bounds__(256)
__global__ void k_gemm(const float* __restrict__ X, const float* __restrict__ Wg,
                       const float* __restrict__ svec, const float* __restrict__ cvec,
                       const float* __restrict__ b2, float* __restrict__ out, int N) {
    __shared__ float ws[128 * 128];
    __shared__ float xs[64 * 128];
    int tid = threadIdx.x;
    int row0 = blockIdx.x * 64;

    // stage W12 (4096 float4)
    {
        const float4* srcv = (const float4*)Wg;
        float4* dstv = (float4*)ws;
#pragma unroll
        for (int it = 0; it < 16; ++it) dstv[it * 256 + tid] = srcv[it * 256 + tid];
    }
    // stage X rows [row0, row0+64), XOR-swizzle column groups to dodge bank conflicts
#pragma unroll
    for (int it = 0; it < 8; ++it) {
        int idx = it * 256 + tid;
        int r = idx >> 5, cg = idx & 31;
        int grow = row0 + r;
        float4 v = make_float4(0.f, 0.f, 0.f, 0.f);
        if (grow < N) v = *(const float4*)(X + (size_t)grow * 128 + cg * 4);
        int c0 = (cg * 4) ^ ((r & 7) << 2);
        *(float4*)&xs[r * 128 + c0] = v;
    }
    __syncthreads();

    int ty = tid >> 4, tx = tid & 15;  // 16x16 threads
    int r0 = ty * 4;                   // 4 rows per thread
    float acc0[4][4] = {{0.f}};        // cols 4tx..4tx+3
    float acc1[4][4] = {{0.f}};        // cols 64+4tx..+3

#pragma unroll 8
    for (int k = 0; k < 128; ++k) {
        float4 w0 = *(const float4*)&ws[k * 128 + 4 * tx];
        float4 w1 = *(const float4*)&ws[k * 128 + 64 + 4 * tx];
        float a[4];
#pragma unroll
        for (int j = 0; j < 4; ++j) {
            int r = r0 + j;
            a[j] = xs[r * 128 + (k ^ ((r & 7) << 2))];
        }
#pragma unroll
        for (int j = 0; j < 4; ++j) {
            acc0[j][0] = fmaf(a[j], w0.x, acc0[j][0]);
            acc0[j][1] = fmaf(a[j], w0.y, acc0[j][1]);
            acc0[j][2] = fmaf(a[j], w0.z, acc0[j][2]);
            acc0[j][3] = fmaf(a[j], w0.w, acc0[j][3]);
            acc1[j][0] = fmaf(a[j], w1.x, acc1[j][0]);
            acc1[j][1] = fmaf(a[j], w1.y, acc1[j][1]);
            acc1[j][2] = fmaf(a[j], w1.z, acc1[j][2]);
            acc1[j][3] = fmaf(a[j], w1.w, acc1[j][3]);
        }
    }

    float c0v[4], c1v[4], b0v[4], b1v[4];
#pragma unroll
    for (int m = 0; m < 4; ++m) {
        c0v[m] = cvec[4 * tx + m];
        c1v[m] = cvec[64 + 4 * tx + m];
        b0v[m] = b2[4 * tx + m];
        b1v[m] = b2[64 + 4 * tx + m];
    }
#pragma unroll
    for (int j = 0; j < 4; ++j) {
        int grow = row0 + r0 + j;
        if (grow >= N) continue;
        float sv = svec[grow];
        float4 o0, o1;
        o0.x = fmaxf(acc0[j][0] + sv * c0v[0] + b0v[0], 0.f);
        o0.y = fmaxf(acc0[j][1] + sv * c0v[1] + b0v[1], 0.f);
        o0.z = fmaxf(acc0[j][2] + sv * c0v[2] + b0v[2], 0.f);
        o0.w = fmaxf(acc0[j][3] + sv * c0v[3] + b0v[3], 0.f);
        o1.x = fmaxf(acc1[j][0] + sv * c1v[0] + b1v[0], 0.f);
        o1.y = fmaxf(acc1[j][1] + sv * c1v[1] + b1v[1], 0.f);
        o1.z = fmaxf(acc1[j][2] + sv * c1v[2] + b1v[2], 0.f);
        o1.w = fmaxf(acc1[j][3] + sv * c1v[3] + b1v[3], 0.f);
        *(float4*)&out[(size_t)grow * 128 + 4 * tx] = o0;
        *(float4*)&out[(size_t)grow * 128 + 64 + 4 * tx] = o1;
    }
}

extern "C" void kernel_launch(void* const* d_in, const int* in_sizes, int n_in,
                              void* d_out, int out_size, void* d_ws, size_t ws_size,
                              hipStream_t stream) {
    const float* x  = (const float*)d_in[0];
    const int*   ei = (const int*)d_in[1];
    const float* W1 = (const float*)d_in[2];
    const float* b1 = (const float*)d_in[3];
    const float* W2 = (const float*)d_in[4];
    const float* b2 = (const float*)d_in[5];
    float* out = (float*)d_out;

    int N = in_sizes[0] / 128;
    int E = in_sizes[1] / 2;
    const int* srcE = ei;
    const int* dstE = ei + E;

    char* w = (char*)d_ws;
    size_t off = 0;
    auto alloc = [&](size_t bytes) {
        void* p = w + off;
        off = WS_ALIGN(off + bytes);
        return p;
    };
    float* t2     = (float*)alloc((size_t)N * 128 * 4);
    int*   csr    = (int*)alloc((size_t)E * 4);
    int*   deg    = (int*)alloc((size_t)N * 4);
    int*   offs   = (int*)alloc((size_t)(N + 1) * 4);
    int*   cursor = (int*)alloc((size_t)N * 4);
    int*   bsums  = (int*)alloc(4096);
    float* dinv   = (float*)alloc((size_t)N * 4);
    float* svec   = (float*)alloc((size_t)N * 4);
    float* w12    = (float*)alloc(128 * 128 * 4);
    float* cvec   = (float*)alloc(128 * 4);
    (void)ws_size; (void)n_in; (void)out_size;

    int nb = (N + 255) / 256;  // 391 for N=100000, fits k_scan2's 512

    k_init_deg<<<(N + 255) / 256, 256, 0, stream>>>(deg, N);
    k_degree<<<(E + 255) / 256, 256, 0, stream>>>(dstE, deg, E, N);
    k_dinv<<<(N + 255) / 256, 256, 0, stream>>>(deg, dinv, N);
    k_scan1<<<nb, 256, 0, stream>>>(deg, offs, bsums, N);
    k_scan2<<<1, 512, 0, stream>>>(bsums, nb);
    k_scan3<<<nb, 256, 0, stream>>>(offs, bsums, cursor, N, E);
    k_fill<<<(E + 255) / 256, 256, 0, stream>>>(srcE, dstE, cursor, csr, E, N);
    // pass 1: t1 = A x  (stored in d_out as scratch), also svec = A·1
    k_agg<1><<<(N + 3) / 4, 256, 0, stream>>>(x, out, offs, csr, dinv, svec, N);
    // pass 2: t2 = A t1
    k_agg<0><<<(N + 3) / 4, 256, 0, stream>>>(out, t2, offs, csr, dinv, nullptr, N);
    k_w12<<<64, 256, 0, stream>>>(W1, W2, w12);
    k_cvec<<<1, 128, 0, stream>>>(b1, W2, cvec);
    // out = relu(t2 @ W12 + svec ⊗ cvec + b2)
    k_gemm<<<(N + 63) / 64, 256, 0, stream>>>(t2, w12, svec, cvec, b2, out, N);
}

// Round 2
// 551.351 us; speedup vs baseline: 1.0573x; 1.0573x over previous
//
#include <hip/hip_runtime.h>

// GCN 2-layer fused:  out = relu( A·(A·x)·(W1@W2) + (A·1)⊗(b1ᵀW2) + b2 )
// A = D^-1/2 (Adj + I) D^-1/2, D = in-degree (dst-side) incl. self-loop.

#define WS_ALIGN(x) (((x) + 255) & ~(size_t)255)

__global__ void k_init_deg(int* __restrict__ deg, int N) {
    int i = blockIdx.x * blockDim.x + threadIdx.x;
    if (i < N) deg[i] = 1;   // self-loop
}

// 8 edges/thread: 8 independent atomic chains in flight per lane (MLP).
__global__ void k_degree(const int* __restrict__ dst, int* __restrict__ deg, int E, int N) {
    int tid = blockIdx.x * blockDim.x + threadIdx.x;
    int stride = gridDim.x * blockDim.x;
#pragma unroll
    for (int it = 0; it < 8; ++it) {
        int e = tid + it * stride;
        if (e < E) {
            int d = dst[e];
            if ((unsigned)d < (unsigned)N) atomicAdd(&deg[d], 1);
        }
    }
}

__global__ void k_dinv(const int* __restrict__ deg, float* __restrict__ dinv, int N) {
    int i = blockIdx.x * blockDim.x + threadIdx.x;
    if (i < N) dinv[i] = rsqrtf((float)deg[i]);
}

// Block-local exclusive scan of indeg = deg-1 (256/block), emits block sums.
__global__ void k_scan1(const int* __restrict__ deg, int* __restrict__ offs,
                        int* __restrict__ bsums, int N) {
    __shared__ int sh[256];
    int i = blockIdx.x * 256 + threadIdx.x;
    int v = (i < N) ? (deg[i] - 1) : 0;
    sh[threadIdx.x] = v;
    __syncthreads();
    for (int off = 1; off < 256; off <<= 1) {
        int t = (threadIdx.x >= off) ? sh[threadIdx.x - off] : 0;
        __syncthreads();
        sh[threadIdx.x] += t;
        __syncthreads();
    }
    if (i < N) offs[i] = sh[threadIdx.x] - v;
    if (threadIdx.x == 255) bsums[blockIdx.x] = sh[255];
}

// Exclusive scan of up to 512 block sums in one block.
__global__ void k_scan2(int* __restrict__ bsums, int nb) {
    __shared__ int sh[512];
    int tid = threadIdx.x;
    int v = (tid < nb) ? bsums[tid] : 0;
    sh[tid] = v;
    __syncthreads();
    for (int off = 1; off < 512; off <<= 1) {
        int t = (tid >= off) ? sh[tid - off] : 0;
        __syncthreads();
        sh[tid] += t;
        __syncthreads();
    }
    if (tid < nb) bsums[tid] = sh[tid] - v;
}

__global__ void k_scan3(int* __restrict__ offs, const int* __restrict__ bsums,
                        int* __restrict__ cursor, int N, int E) {
    int i = blockIdx.x * 256 + threadIdx.x;
    if (i < N) {
        int o = offs[i] + bsums[blockIdx.x];
        offs[i] = o;
        cursor[i] = o;
    }
    if (blockIdx.x == 0 && threadIdx.x == 0) offs[N] = E;
}

// CSR fill, 8 edges/thread for atomic-return MLP. Position order within a
// segment is arbitrary (only changes fp sum order — within threshold).
__global__ void k_fill(const int* __restrict__ src, const int* __restrict__ dst,
                       int* __restrict__ cursor, int* __restrict__ csr, int E, int N) {
    int tid = blockIdx.x * blockDim.x + threadIdx.x;
    int stride = gridDim.x * blockDim.x;
    int dd[8], ss[8], pos[8];
    bool ok[8];
#pragma unroll
    for (int it = 0; it < 8; ++it) {
        int e = tid + it * stride;
        bool v = (e < E);
        int d = v ? dst[e] : 0;
        int s = v ? src[e] : 0;
        ok[it] = v && (unsigned)d < (unsigned)N && (unsigned)s < (unsigned)N;
        dd[it] = d;
        ss[it] = s;
    }
#pragma unroll
    for (int it = 0; it < 8; ++it)
        if (ok[it]) pos[it] = atomicAdd(&cursor[dd[it]], 1);
#pragma unroll
    for (int it = 0; it < 8; ++it)
        if (ok[it]) csr[pos[it]] = ss[it];
}

// Pull aggregation: out[i] = dinv[i] * ( dinv[i]*x[i] + sum_{s in in(i)} dinv[s]*x[s] )
// One wave per node. Lanes 0-31 process neighbor t (float4 = full 512B row per
// half-wave), lanes 32-63 neighbor t+1: 1KB per paired iteration, unroll 4
// => ~4KB in flight per wave. Halves combined via __shfl(lane+32) at the end.
template <int WITH_S>
__launch_bounds__(256)
__global__ void k_agg(const float* __restrict__ xin, float* __restrict__ xout,
                      const int* __restrict__ offs, const int* __restrict__ csr,
                      const float* __restrict__ dinv, float* __restrict__ svec, int N) {
    int gw = (int)((blockIdx.x * (size_t)blockDim.x + threadIdx.x) >> 6);
    int lane = threadIdx.x & 63;
    if (gw >= N) return;
    int halfid = lane >> 5;
    int hl = lane & 31;
    float di = dinv[gw];

    float4 acc = make_float4(0.f, 0.f, 0.f, 0.f);
    if (halfid == 0) {
        float4 v = *(const float4*)(xin + (size_t)gw * 128 + hl * 4);
        acc.x = di * v.x;
        acc.y = di * v.y;
        acc.z = di * v.z;
        acc.w = di * v.w;
    }
    float ssum = (halfid == 0) ? di : 0.f;

    int s0 = offs[gw], s1 = offs[gw + 1];
    for (int base = s0; base < s1; base += 64) {
        int cnt = min(64, s1 - base);
        int sidx = 0;
        float dv = 0.f;  // lanes >= cnt keep dv=0 -> padded slots contribute 0
        if (lane < cnt) {
            sidx = csr[base + lane];
            dv = dinv[sidx];
        }
        int iters = (cnt + 1) >> 1;
#pragma unroll 4
        for (int i = 0; i < iters; ++i) {
            int t = 2 * i + halfid;          // <= 63 always
            int s = __shfl(sidx, t);
            float d = __shfl(dv, t);
            const float4 v = *(const float4*)(xin + (size_t)s * 128 + hl * 4);
            acc.x = fmaf(d, v.x, acc.x);
            acc.y = fmaf(d, v.y, acc.y);
            acc.z = fmaf(d, v.z, acc.z);
            acc.w = fmaf(d, v.w, acc.w);
            if (WITH_S) ssum += d;
        }
    }

    // combine the two halves (lane+32 wraps mod 64 -> partner lane)
    acc.x += __shfl(acc.x, lane + 32);
    acc.y += __shfl(acc.y, lane + 32);
    acc.z += __shfl(acc.z, lane + 32);
    acc.w += __shfl(acc.w, lane + 32);
    if (halfid == 0) {
        acc.x *= di;
        acc.y *= di;
        acc.z *= di;
        acc.w *= di;
        *(float4*)(xout + (size_t)gw * 128 + hl * 4) = acc;
    }
    if (WITH_S) {
        float so = __shfl(ssum, lane + 32);
        if (lane == 0) svec[gw] = di * (ssum + so);
    }
}

// W12 = W1 @ W2  (128x128 @ 128x128), one output per thread.
__global__ void k_w12(const float* __restrict__ W1, const float* __restrict__ W2,
                      float* __restrict__ w12) {
    int idx = blockIdx.x * 256 + threadIdx.x;  // 0..16383
    int i = idx >> 7, j = idx & 127;
    float s = 0.f;
#pragma unroll 8
    for (int k = 0; k < 128; ++k) s = fmaf(W1[i * 128 + k], W2[k * 128 + j], s);
    w12[idx] = s;
}

// cvec = b1^T @ W2  (128,)
__global__ void k_cvec(const float* __restrict__ b1, const float* __restrict__ W2,
                       float* __restrict__ cvec) {
    int j = threadIdx.x;
    float s = 0.f;
#pragma unroll 8
    for (int k = 0; k < 128; ++k) s = fmaf(b1[k], W2[k * 128 + j], s);
    cvec[j] = s;
}

// out = relu( X @ W12 + svec ⊗ cvec + b2 )  — fp32 vector GEMM, LDS-tiled.
// Block: 256 threads, 64 rows. W12 (64KB) + x tile (32KB, XOR-swizzled) in LDS.
__launch_bounds__(256)
__global__ void k_gemm(const float* __restrict__ X, const float* __restrict__ Wg,
                       const float* __restrict__ svec, const float* __restrict__ cvec,
                       const float* __restrict__ b2, float* __restrict__ out, int N) {
    __shared__ float ws[128 * 128];
    __shared__ float xs[64 * 128];
    int tid = threadIdx.x;
    int row0 = blockIdx.x * 64;

    // stage W12 (4096 float4)
    {
        const float4* srcv = (const float4*)Wg;
        float4* dstv = (float4*)ws;
#pragma unroll
        for (int it = 0; it < 16; ++it) dstv[it * 256 + tid] = srcv[it * 256 + tid];
    }
    // stage X rows [row0, row0+64), XOR-swizzle column groups to dodge bank conflicts
#pragma unroll
    for (int it = 0; it < 8; ++it) {
        int idx = it * 256 + tid;
        int r = idx >> 5, cg = idx & 31;
        int grow = row0 + r;
        float4 v = make_float4(0.f, 0.f, 0.f, 0.f);
        if (grow < N) v = *(const float4*)(X + (size_t)grow * 128 + cg * 4);
        int c0 = (cg * 4) ^ ((r & 7) << 2);
        *(float4*)&xs[r * 128 + c0] = v;
    }
    __syncthreads();

    int ty = tid >> 4, tx = tid & 15;  // 16x16 threads
    int r0 = ty * 4;                   // 4 rows per thread
    float acc0[4][4] = {{0.f}};        // cols 4tx..4tx+3
    float acc1[4][4] = {{0.f}};        // cols 64+4tx..+3

#pragma unroll 8
    for (int k = 0; k < 128; ++k) {
        float4 w0 = *(const float4*)&ws[k * 128 + 4 * tx];
        float4 w1 = *(const float4*)&ws[k * 128 + 64 + 4 * tx];
        float a[4];
#pragma unroll
        for (int j = 0; j < 4; ++j) {
            int r = r0 + j;
            a[j] = xs[r * 128 + (k ^ ((r & 7) << 2))];
        }
#pragma unroll
        for (int j = 0; j < 4; ++j) {
            acc0[j][0] = fmaf(a[j], w0.x, acc0[j][0]);
            acc0[j][1] = fmaf(a[j], w0.y, acc0[j][1]);
            acc0[j][2] = fmaf(a[j], w0.z, acc0[j][2]);
            acc0[j][3] = fmaf(a[j], w0.w, acc0[j][3]);
            acc1[j][0] = fmaf(a[j], w1.x, acc1[j][0]);
            acc1[j][1] = fmaf(a[j], w1.y, acc1[j][1]);
            acc1[j][2] = fmaf(a[j], w1.z, acc1[j][2]);
            acc1[j][3] = fmaf(a[j], w1.w, acc1[j][3]);
        }
    }

    float c0v[4], c1v[4], b0v[4], b1v[4];
#pragma unroll
    for (int m = 0; m < 4; ++m) {
        c0v[m] = cvec[4 * tx + m];
        c1v[m] = cvec[64 + 4 * tx + m];
        b0v[m] = b2[4 * tx + m];
        b1v[m] = b2[64 + 4 * tx + m];
    }
#pragma unroll
    for (int j = 0; j < 4; ++j) {
        int grow = row0 + r0 + j;
        if (grow >= N) continue;
        float sv = svec[grow];
        float4 o0, o1;
        o0.x = fmaxf(acc0[j][0] + sv * c0v[0] + b0v[0], 0.f);
        o0.y = fmaxf(acc0[j][1] + sv * c0v[1] + b0v[1], 0.f);
        o0.z = fmaxf(acc0[j][2] + sv * c0v[2] + b0v[2], 0.f);
        o0.w = fmaxf(acc0[j][3] + sv * c0v[3] + b0v[3], 0.f);
        o1.x = fmaxf(acc1[j][0] + sv * c1v[0] + b1v[0], 0.f);
        o1.y = fmaxf(acc1[j][1] + sv * c1v[1] + b1v[1], 0.f);
        o1.z = fmaxf(acc1[j][2] + sv * c1v[2] + b1v[2], 0.f);
        o1.w = fmaxf(acc1[j][3] + sv * c1v[3] + b1v[3], 0.f);
        *(float4*)&out[(size_t)grow * 128 + 4 * tx] = o0;
        *(float4*)&out[(size_t)grow * 128 + 64 + 4 * tx] = o1;
    }
}

extern "C" void kernel_launch(void* const* d_in, const int* in_sizes, int n_in,
                              void* d_out, int out_size, void* d_ws, size_t ws_size,
                              hipStream_t stream) {
    const float* x  = (const float*)d_in[0];
    const int*   ei = (const int*)d_in[1];
    const float* W1 = (const float*)d_in[2];
    const float* b1 = (const float*)d_in[3];
    const float* W2 = (const float*)d_in[4];
    const float* b2 = (const float*)d_in[5];
    float* out = (float*)d_out;

    int N = in_sizes[0] / 128;
    int E = in_sizes[1] / 2;
    const int* srcE = ei;
    const int* dstE = ei + E;

    char* w = (char*)d_ws;
    size_t off = 0;
    auto alloc = [&](size_t bytes) {
        void* p = w + off;
        off = WS_ALIGN(off + bytes);
        return p;
    };
    float* t2     = (float*)alloc((size_t)N * 128 * 4);
    int*   csr    = (int*)alloc((size_t)E * 4);
    int*   deg    = (int*)alloc((size_t)N * 4);
    int*   offs   = (int*)alloc((size_t)(N + 1) * 4);
    int*   cursor = (int*)alloc((size_t)N * 4);
    int*   bsums  = (int*)alloc(4096);
    float* dinv   = (float*)alloc((size_t)N * 4);
    float* svec   = (float*)alloc((size_t)N * 4);
    float* w12    = (float*)alloc(128 * 128 * 4);
    float* cvec   = (float*)alloc(128 * 4);
    (void)ws_size; (void)n_in; (void)out_size;

    int nb = (N + 255) / 256;  // 391 for N=100000, fits k_scan2's 512
    int fill_blocks = (E + 8 * 256 - 1) / (8 * 256);

    k_init_deg<<<(N + 255) / 256, 256, 0, stream>>>(deg, N);
    k_degree<<<fill_blocks, 256, 0, stream>>>(dstE, deg, E, N);
    k_dinv<<<(N + 255) / 256, 256, 0, stream>>>(deg, dinv, N);
    k_scan1<<<nb, 256, 0, stream>>>(deg, offs, bsums, N);
    k_scan2<<<1, 512, 0, stream>>>(bsums, nb);
    k_scan3<<<nb, 256, 0, stream>>>(offs, bsums, cursor, N, E);
    k_fill<<<fill_blocks, 256, 0, stream>>>(srcE, dstE, cursor, csr, E, N);
    // pass 1: t1 = A x  (stored in d_out as scratch), also svec = A·1
    k_agg<1><<<(N + 3) / 4, 256, 0, stream>>>(x, out, offs, csr, dinv, svec, N);
    // pass 2: t2 = A t1
    k_agg<0><<<(N + 3) / 4, 256, 0, stream>>>(out, t2, offs, csr, dinv, nullptr, N);
    k_w12<<<64, 256, 0, stream>>>(W1, W2, w12);
    k_cvec<<<1, 128, 0, stream>>>(b1, W2, cvec);
    // out = relu(t2 @ W12 + svec ⊗ cvec + b2)
    k_gemm<<<(N + 63) / 64, 256, 0, stream>>>(t2, w12, svec, cvec, b2, out, N);
}

// Round 5
// 386.790 us; speedup vs baseline: 1.5071x; 1.4255x over previous
//
#include <hip/hip_runtime.h>

// GCN 2-layer fused:  out = relu( A·(A·x)·(W1@W2) + (A·1)⊗(b1ᵀW2) + b2 )
// A = D^-1/2 (Adj + I) D^-1/2.  Both aggregation passes gather int16 rows
// with per-row dynamic scale. Pass 2 writes f32 into d_out; GEMM in-place.
// NOTE: all __shfl executed unconditionally (ds_bpermute from an exec-masked
// lane is undefined — this was the round-3/4 correctness bug).

#define WS_ALIGN(x) (((x) + 255) & ~(size_t)255)

__global__ void k_init_deg(int* __restrict__ deg, int N) {
    int i = blockIdx.x * blockDim.x + threadIdx.x;
    if (i < N) deg[i] = 0;   // real edges only; self-loop added in dinv
}

// degree count + within-segment rank (atomicAdd return). rank write coalesced.
__global__ void k_rank(const int* __restrict__ dst, int* __restrict__ deg,
                       int* __restrict__ rank, int E, int N) {
    int tid = blockIdx.x * blockDim.x + threadIdx.x;
    int stride = gridDim.x * blockDim.x;
#pragma unroll
    for (int it = 0; it < 8; ++it) {
        int e = tid + it * stride;
        if (e < E) {
            int d = dst[e];
            if ((unsigned)d < (unsigned)N) rank[e] = atomicAdd(&deg[d], 1);
        }
    }
}

__global__ void k_dinv(const int* __restrict__ deg, float* __restrict__ dinv, int N) {
    int i = blockIdx.x * blockDim.x + threadIdx.x;
    if (i < N) dinv[i] = rsqrtf((float)(deg[i] + 1));
}

// Block-local exclusive scan of deg (256/block), emits block sums.
__global__ void k_scan1(const int* __restrict__ deg, int* __restrict__ offs,
                        int* __restrict__ bsums, int N) {
    __shared__ int sh[256];
    int i = blockIdx.x * 256 + threadIdx.x;
    int v = (i < N) ? deg[i] : 0;
    sh[threadIdx.x] = v;
    __syncthreads();
    for (int off = 1; off < 256; off <<= 1) {
        int t = (threadIdx.x >= off) ? sh[threadIdx.x - off] : 0;
        __syncthreads();
        sh[threadIdx.x] += t;
        __syncthreads();
    }
    if (i < N) offs[i] = sh[threadIdx.x] - v;
    if (threadIdx.x == 255) bsums[blockIdx.x] = sh[255];
}

// Exclusive scan of up to 512 block sums in one block.
__global__ void k_scan2(int* __restrict__ bsums, int nb) {
    __shared__ int sh[512];
    int tid = threadIdx.x;
    int v = (tid < nb) ? bsums[tid] : 0;
    sh[tid] = v;
    __syncthreads();
    for (int off = 1; off < 512; off <<= 1) {
        int t = (tid >= off) ? sh[tid - off] : 0;
        __syncthreads();
        sh[tid] += t;
        __syncthreads();
    }
    if (tid < nb) bsums[tid] = sh[tid] - v;
}

__global__ void k_scan3(int* __restrict__ offs, const int* __restrict__ bsums, int N, int E) {
    int i = blockIdx.x * 256 + threadIdx.x;
    if (i < N) offs[i] += bsums[blockIdx.x];
    if (blockIdx.x == 0 && threadIdx.x == 0) offs[N] = E;
}

// Atomic-free CSR fill: slot = offs[dst] + rank. Fire-and-forget scatter.
__global__ void k_fill(const int* __restrict__ src, const int* __restrict__ dst,
                       const int* __restrict__ rank, const int* __restrict__ offs,
                       int* __restrict__ csr, int E, int N) {
    int tid = blockIdx.x * blockDim.x + threadIdx.x;
    int stride = gridDim.x * blockDim.x;
#pragma unroll
    for (int it = 0; it < 8; ++it) {
        int e = tid + it * stride;
        if (e < E) {
            int d = dst[e];
            int s = src[e];
            int r = rank[e];
            if ((unsigned)d < (unsigned)N && (unsigned)s < (unsigned)N)
                csr[offs[d] + r] = s;
        }
    }
}

// x (f32) -> int16 with per-row scale. One wave per row; lane owns 2 elems.
// meta[i] = (dinv[i], dinv[i]*scale[i]) -> the fused gather weight.
__launch_bounds__(256)
__global__ void k_toq16(const float* __restrict__ x, const float* __restrict__ dinv,
                        ushort* __restrict__ xq, float2* __restrict__ meta, int N) {
    int gw = (int)((blockIdx.x * (size_t)blockDim.x + threadIdx.x) >> 6);
    int lane = threadIdx.x & 63;
    if (gw >= N) return;
    float2 v = ((const float2*)(x + (size_t)gw * 128))[lane];
    float m = fmaxf(fabsf(v.x), fabsf(v.y));
#pragma unroll
    for (int d = 1; d < 64; d <<= 1) m = fmaxf(m, __shfl_xor(m, d));
    float inv = (m > 0.f) ? 32767.f / m : 0.f;
    int qa = __float2int_rn(v.x * inv);
    int qb = __float2int_rn(v.y * inv);
    uint packed = ((uint)qa & 0xFFFFu) | ((uint)qb << 16);
    ((uint*)xq)[(size_t)gw * 64 + lane] = packed;
    if (lane == 0) {
        float di = dinv[gw];
        meta[gw] = make_float2(di, di * (m * (1.f / 32767.f)));
    }
}

__device__ inline void unpackq(uint4 v, float f[8]) {
    f[0] = (float)(short)(v.x & 0xFFFFu);
    f[1] = (float)((int)v.x >> 16);
    f[2] = (float)(short)(v.y & 0xFFFFu);
    f[3] = (float)((int)v.y >> 16);
    f[4] = (float)(short)(v.z & 0xFFFFu);
    f[5] = (float)((int)v.z >> 16);
    f[6] = (float)(short)(v.w & 0xFFFFu);
    f[7] = (float)((int)v.w >> 16);
}

// Aggregation over int16 rows. One wave per node; quarter-wave (16 lanes)
// covers a 256B int16 row via uint4 -> 4 neighbor rows in flight/iteration.
// Gather weight per neighbor s = meta[s].y = dinv[s]*scale[s].
// WRITE_Q=1: re-quantize output to int16 (qout,mout) + svec = rowsum(A).
// WRITE_Q=0: write f32 rows to fout.
template <int WRITE_Q>
__launch_bounds__(256)
__global__ void k_aggq(const ushort* __restrict__ xq, const float2* __restrict__ meta,
                       float* __restrict__ fout,
                       ushort* __restrict__ qout, float2* __restrict__ mout,
                       float* __restrict__ svec,
                       const int* __restrict__ offs, const int* __restrict__ csr, int N) {
    int gw = (int)((blockIdx.x * (size_t)blockDim.x + threadIdx.x) >> 6);
    int lane = threadIdx.x & 63;
    if (gw >= N) return;
    int q = lane >> 4, ql = lane & 15;
    float2 ms = meta[gw];
    float di = ms.x;

    float acc[8];
#pragma unroll
    for (int j = 0; j < 8; ++j) acc[j] = 0.f;
    float ssum = (lane == 0) ? di : 0.f;

    if (q == 0) {  // self term: weight di*scale_self = ms.y
        uint4 v = *(const uint4*)(xq + (size_t)gw * 128 + ql * 8);
        float f[8];
        unpackq(v, f);
#pragma unroll
        for (int j = 0; j < 8; ++j) acc[j] = ms.y * f[j];
    }

    int s0 = offs[gw], s1 = offs[gw + 1];
    for (int base = s0; base < s1; base += 64) {
        int cnt = min(64, s1 - base);
        int sidx = 0;
        float wv = 0.f, dv = 0.f;   // lanes >= cnt keep 0 -> d==0 for padded t
        if (lane < cnt) {
            sidx = csr[base + lane];
            float2 mm = meta[sidx];
            dv = mm.x;
            wv = mm.y;
        }
        int iters = (cnt + 3) >> 2;
#pragma unroll 4
        for (int i = 0; i < iters; ++i) {
            int t = 4 * i + q;          // t <= 63 always
            // __shfl OUTSIDE any divergent guard: every source lane is active
            // and holds valid (possibly zero-padded) data.
            int s = __shfl(sidx, t);
            float d = __shfl(wv, t);
            float dd = 0.f;
            if (WRITE_Q) dd = __shfl(dv, t);   // compile-time uniform branch
            if (t < cnt) {
                uint4 v = *(const uint4*)(xq + (size_t)s * 128 + ql * 8);
                float f[8];
                unpackq(v, f);
#pragma unroll
                for (int j = 0; j < 8; ++j) acc[j] = fmaf(d, f[j], acc[j]);
                if (WRITE_Q && ql == 0) ssum += dd;
            }
        }
    }

    // butterfly combine: afterwards EVERY lane holds the full sum of its slice
#pragma unroll
    for (int j = 0; j < 8; ++j) {
        acc[j] += __shfl_xor(acc[j], 16);
        acc[j] += __shfl_xor(acc[j], 32);
        acc[j] *= di;
    }

    if (WRITE_Q) {
        ssum += __shfl_xor(ssum, 16);
        ssum += __shfl_xor(ssum, 32);
        if (lane == 0) svec[gw] = di * ssum;
        // row max over the 16 feature slices (all lanes have full slice sums)
        float m = 0.f;
#pragma unroll
        for (int j = 0; j < 8; ++j) m = fmaxf(m, fabsf(acc[j]));
#pragma unroll
        for (int d = 1; d < 16; d <<= 1) m = fmaxf(m, __shfl_xor(m, d));
        float inv = (m > 0.f) ? 32767.f / m : 0.f;
        if (q == 0) {
            uint4 o;
            int q0 = __float2int_rn(acc[0] * inv), q1 = __float2int_rn(acc[1] * inv);
            int q2 = __float2int_rn(acc[2] * inv), q3 = __float2int_rn(acc[3] * inv);
            int q4 = __float2int_rn(acc[4] * inv), q5 = __float2int_rn(acc[5] * inv);
            int q6 = __float2int_rn(acc[6] * inv), q7 = __float2int_rn(acc[7] * inv);
            o.x = ((uint)q0 & 0xFFFFu) | ((uint)q1 << 16);
            o.y = ((uint)q2 & 0xFFFFu) | ((uint)q3 << 16);
            o.z = ((uint)q4 & 0xFFFFu) | ((uint)q5 << 16);
            o.w = ((uint)q6 & 0xFFFFu) | ((uint)q7 << 16);
            *(uint4*)(qout + (size_t)gw * 128 + ql * 8) = o;
        }
        if (lane == 0) mout[gw] = make_float2(di, di * (m * (1.f / 32767.f)));
    } else {
        if (q == 0) {
            float4 o0, o1;
            o0.x = acc[0]; o0.y = acc[1]; o0.z = acc[2]; o0.w = acc[3];
            o1.x = acc[4]; o1.y = acc[5]; o1.z = acc[6]; o1.w = acc[7];
            *(float4*)(fout + (size_t)gw * 128 + ql * 8) = o0;
            *(float4*)(fout + (size_t)gw * 128 + ql * 8 + 4) = o1;
        }
    }
}

// W12 = W1 @ W2  (128x128 @ 128x128), one output per thread.
__global__ void k_w12(const float* __restrict__ W1, const float* __restrict__ W2,
                      float* __restrict__ w12) {
    int idx = blockIdx.x * 256 + threadIdx.x;  // 0..16383
    int i = idx >> 7, j = idx & 127;
    float s = 0.f;
#pragma unroll 8
    for (int k = 0; k < 128; ++k) s = fmaf(W1[i * 128 + k], W2[k * 128 + j], s);
    w12[idx] = s;
}

// cvec = b1^T @ W2  (128,)
__global__ void k_cvec(const float* __restrict__ b1, const float* __restrict__ W2,
                       float* __restrict__ cvec) {
    int j = threadIdx.x;
    float s = 0.f;
#pragma unroll 8
    for (int k = 0; k < 128; ++k) s = fmaf(b1[k], W2[k * 128 + j], s);
    cvec[j] = s;
}

// out = relu( X @ W12 + svec ⊗ cvec + b2 ) — fp32 vector GEMM, LDS-tiled.
// Safe in-place (X == out): each block stages its 64 rows into LDS before
// writing them, and blocks touch disjoint rows.
__launch_bounds__(256)
__global__ void k_gemm(const float* __restrict__ X, const float* __restrict__ Wg,
                       const float* __restrict__ svec, const float* __restrict__ cvec,
                       const float* __restrict__ b2, float* __restrict__ out, int N) {
    __shared__ float ws[128 * 128];
    __shared__ float xs[64 * 128];
    int tid = threadIdx.x;
    int row0 = blockIdx.x * 64;

    {
        const float4* srcv = (const float4*)Wg;
        float4* dstv = (float4*)ws;
#pragma unroll
        for (int it = 0; it < 16; ++it) dstv[it * 256 + tid] = srcv[it * 256 + tid];
    }
#pragma unroll
    for (int it = 0; it < 8; ++it) {
        int idx = it * 256 + tid;
        int r = idx >> 5, cg = idx & 31;
        int grow = row0 + r;
        float4 v = make_float4(0.f, 0.f, 0.f, 0.f);
        if (grow < N) v = *(const float4*)(X + (size_t)grow * 128 + cg * 4);
        int c0 = (cg * 4) ^ ((r & 7) << 2);
        *(float4*)&xs[r * 128 + c0] = v;
    }
    __syncthreads();

    int ty = tid >> 4, tx = tid & 15;
    int r0 = ty * 4;
    float acc0[4][4] = {{0.f}};
    float acc1[4][4] = {{0.f}};

#pragma unroll 8
    for (int k = 0; k < 128; ++k) {
        float4 w0 = *(const float4*)&ws[k * 128 + 4 * tx];
        float4 w1 = *(const float4*)&ws[k * 128 + 64 + 4 * tx];
        float a[4];
#pragma unroll
        for (int j = 0; j < 4; ++j) {
            int r = r0 + j;
            a[j] = xs[r * 128 + (k ^ ((r & 7) << 2))];
        }
#pragma unroll
        for (int j = 0; j < 4; ++j) {
            acc0[j][0] = fmaf(a[j], w0.x, acc0[j][0]);
            acc0[j][1] = fmaf(a[j], w0.y, acc0[j][1]);
            acc0[j][2] = fmaf(a[j], w0.z, acc0[j][2]);
            acc0[j][3] = fmaf(a[j], w0.w, acc0[j][3]);
            acc1[j][0] = fmaf(a[j], w1.x, acc1[j][0]);
            acc1[j][1] = fmaf(a[j], w1.y, acc1[j][1]);
            acc1[j][2] = fmaf(a[j], w1.z, acc1[j][2]);
            acc1[j][3] = fmaf(a[j], w1.w, acc1[j][3]);
        }
    }

    float c0v[4], c1v[4], b0v[4], b1v[4];
#pragma unroll
    for (int m = 0; m < 4; ++m) {
        c0v[m] = cvec[4 * tx + m];
        c1v[m] = cvec[64 + 4 * tx + m];
        b0v[m] = b2[4 * tx + m];
        b1v[m] = b2[64 + 4 * tx + m];
    }
#pragma unroll
    for (int j = 0; j < 4; ++j) {
        int grow = row0 + r0 + j;
        if (grow >= N) continue;
        float sv = svec[grow];
        float4 o0, o1;
        o0.x = fmaxf(acc0[j][0] + sv * c0v[0] + b0v[0], 0.f);
        o0.y = fmaxf(acc0[j][1] + sv * c0v[1] + b0v[1], 0.f);
        o0.z = fmaxf(acc0[j][2] + sv * c0v[2] + b0v[2], 0.f);
        o0.w = fmaxf(acc0[j][3] + sv * c0v[3] + b0v[3], 0.f);
        o1.x = fmaxf(acc1[j][0] + sv * c1v[0] + b1v[0], 0.f);
        o1.y = fmaxf(acc1[j][1] + sv * c1v[1] + b1v[1], 0.f);
        o1.z = fmaxf(acc1[j][2] + sv * c1v[2] + b1v[2], 0.f);
        o1.w = fmaxf(acc1[j][3] + sv * c1v[3] + b1v[3], 0.f);
        *(float4*)&out[(size_t)grow * 128 + 4 * tx] = o0;
        *(float4*)&out[(size_t)grow * 128 + 64 + 4 * tx] = o1;
    }
}

extern "C" void kernel_launch(void* const* d_in, const int* in_sizes, int n_in,
                              void* d_out, int out_size, void* d_ws, size_t ws_size,
                              hipStream_t stream) {
    const float* x  = (const float*)d_in[0];
    const int*   ei = (const int*)d_in[1];
    const float* W1 = (const float*)d_in[2];
    const float* b1 = (const float*)d_in[3];
    const float* W2 = (const float*)d_in[4];
    const float* b2 = (const float*)d_in[5];
    float* out = (float*)d_out;

    int N = in_sizes[0] / 128;
    int E = in_sizes[1] / 2;
    const int* srcE = ei;
    const int* dstE = ei + E;

    char* w = (char*)d_ws;
    size_t off = 0;
    auto alloc = [&](size_t bytes) {
        void* p = w + off;
        off = WS_ALIGN(off + bytes);
        return p;
    };
    ushort* xq   = (ushort*)alloc((size_t)N * 256);
    // union: rank (E*4) dead after k_fill; t1q written later by k_aggq<1>.
    void*  uni   = alloc((size_t)E * 4 > (size_t)N * 256 ? (size_t)E * 4 : (size_t)N * 256);
    int*   rank  = (int*)uni;
    ushort* t1q  = (ushort*)uni;
    int*   csr   = (int*)alloc((size_t)E * 4);
    float2* meta1 = (float2*)alloc((size_t)N * 8);
    float2* meta2 = (float2*)alloc((size_t)N * 8);
    int*   deg   = (int*)alloc((size_t)N * 4);
    int*   offs  = (int*)alloc((size_t)(N + 1) * 4);
    int*   bsums = (int*)alloc(4096);
    float* dinv  = (float*)alloc((size_t)N * 4);
    float* svec  = (float*)alloc((size_t)N * 4);
    float* w12   = (float*)alloc(128 * 128 * 4);
    float* cvec  = (float*)alloc(128 * 4);
    (void)ws_size; (void)n_in; (void)out_size;

    int nb = (N + 255) / 256;  // 391 for N=100000, fits k_scan2's 512
    int eb8 = (E + 8 * 256 - 1) / (8 * 256);

    k_init_deg<<<(N + 255) / 256, 256, 0, stream>>>(deg, N);
    k_rank<<<eb8, 256, 0, stream>>>(dstE, deg, rank, E, N);
    k_dinv<<<(N + 255) / 256, 256, 0, stream>>>(deg, dinv, N);
    k_scan1<<<nb, 256, 0, stream>>>(deg, offs, bsums, N);
    k_scan2<<<1, 512, 0, stream>>>(bsums, nb);
    k_scan3<<<nb, 256, 0, stream>>>(offs, bsums, N, E);
    k_fill<<<eb8, 256, 0, stream>>>(srcE, dstE, rank, offs, csr, E, N);
    // quantize x (rank is dead from here; t1q may overwrite it)
    k_toq16<<<(N + 3) / 4, 256, 0, stream>>>(x, dinv, xq, meta1, N);
    // pass 1: t1 = A x   (int16 in, int16 out) + svec = rowsum(A)
    k_aggq<1><<<(N + 3) / 4, 256, 0, stream>>>(xq, meta1, nullptr, t1q, meta2, svec,
                                               offs, csr, N);
    // pass 2: t2 = A t1  (int16 in, f32 out -> d_out as scratch)
    k_aggq<0><<<(N + 3) / 4, 256, 0, stream>>>(t1q, meta2, out, nullptr, nullptr, nullptr,
                                               offs, csr, N);
    k_w12<<<64, 256, 0, stream>>>(W1, W2, w12);
    k_cvec<<<1, 128, 0, stream>>>(b1, W2, cvec);
    // out = relu(t2 @ W12 + svec ⊗ cvec + b2), in-place on d_out
    k_gemm<<<(N + 63) / 64, 256, 0, stream>>>(out, w12, svec, cvec, b2, out, N);
}

// Round 6
// 350.626 us; speedup vs baseline: 1.6625x; 1.1031x over previous
//
#include <hip/hip_runtime.h>

// GCN 2-layer fused:  out = relu( A·(A·x)·(W1@W2) + (A·1)⊗(b1ᵀW2) + b2 )
// A = D^-1/2 (Adj + I) D^-1/2.  Both aggregation passes gather int16 rows
// with per-row dynamic scale. Pass 2 writes f32 into d_out; GEMM in-place.
// NOTE: all __shfl executed unconditionally (ds_bpermute from an exec-masked
// lane is undefined — this was the round-3/4 correctness bug).

#define WS_ALIGN(x) (((x) + 255) & ~(size_t)255)

__global__ void k_init_deg(int* __restrict__ deg, int N) {
    int i = blockIdx.x * blockDim.x + threadIdx.x;
    if (i < N) deg[i] = 0;   // real edges only; self-loop added in dinv
}

// degree count + within-segment rank (atomicAdd return). rank write coalesced.
__global__ void k_rank(const int* __restrict__ dst, int* __restrict__ deg,
                       int* __restrict__ rank, int E, int N) {
    int tid = blockIdx.x * blockDim.x + threadIdx.x;
    int stride = gridDim.x * blockDim.x;
#pragma unroll
    for (int it = 0; it < 8; ++it) {
        int e = tid + it * stride;
        if (e < E) {
            int d = dst[e];
            if ((unsigned)d < (unsigned)N) rank[e] = atomicAdd(&deg[d], 1);
        }
    }
}

__global__ void k_dinv(const int* __restrict__ deg, float* __restrict__ dinv, int N) {
    int i = blockIdx.x * blockDim.x + threadIdx.x;
    if (i < N) dinv[i] = rsqrtf((float)(deg[i] + 1));
}

// Block-local exclusive scan of deg (256/block), emits block sums.
__global__ void k_scan1(const int* __restrict__ deg, int* __restrict__ offs,
                        int* __restrict__ bsums, int N) {
    __shared__ int sh[256];
    int i = blockIdx.x * 256 + threadIdx.x;
    int v = (i < N) ? deg[i] : 0;
    sh[threadIdx.x] = v;
    __syncthreads();
    for (int off = 1; off < 256; off <<= 1) {
        int t = (threadIdx.x >= off) ? sh[threadIdx.x - off] : 0;
        __syncthreads();
        sh[threadIdx.x] += t;
        __syncthreads();
    }
    if (i < N) offs[i] = sh[threadIdx.x] - v;
    if (threadIdx.x == 255) bsums[blockIdx.x] = sh[255];
}

// Exclusive scan of up to 512 block sums in one block.
__global__ void k_scan2(int* __restrict__ bsums, int nb) {
    __shared__ int sh[512];
    int tid = threadIdx.x;
    int v = (tid < nb) ? bsums[tid] : 0;
    sh[tid] = v;
    __syncthreads();
    for (int off = 1; off < 512; off <<= 1) {
        int t = (tid >= off) ? sh[tid - off] : 0;
        __syncthreads();
        sh[tid] += t;
        __syncthreads();
    }
    if (tid < nb) bsums[tid] = sh[tid] - v;
}

__global__ void k_scan3(int* __restrict__ offs, const int* __restrict__ bsums, int N, int E) {
    int i = blockIdx.x * 256 + threadIdx.x;
    if (i < N) offs[i] += bsums[blockIdx.x];
    if (blockIdx.x == 0 && threadIdx.x == 0) offs[N] = E;
}

// Atomic-free CSR fill: slot = offs[dst] + rank. Fire-and-forget scatter.
__global__ void k_fill(const int* __restrict__ src, const int* __restrict__ dst,
                       const int* __restrict__ rank, const int* __restrict__ offs,
                       int* __restrict__ csr, int E, int N) {
    int tid = blockIdx.x * blockDim.x + threadIdx.x;
    int stride = gridDim.x * blockDim.x;
#pragma unroll
    for (int it = 0; it < 8; ++it) {
        int e = tid + it * stride;
        if (e < E) {
            int d = dst[e];
            int s = src[e];
            int r = rank[e];
            if ((unsigned)d < (unsigned)N && (unsigned)s < (unsigned)N)
                csr[offs[d] + r] = s;
        }
    }
}

// x (f32) -> int16 with per-row scale. One wave per row; lane owns 2 elems.
// meta[i] = (dinv[i], dinv[i]*scale[i]) -> the fused gather weight.
__launch_bounds__(256)
__global__ void k_toq16(const float* __restrict__ x, const float* __restrict__ dinv,
                        ushort* __restrict__ xq, float2* __restrict__ meta, int N) {
    int gw = (int)((blockIdx.x * (size_t)blockDim.x + threadIdx.x) >> 6);
    int lane = threadIdx.x & 63;
    if (gw >= N) return;
    float2 v = ((const float2*)(x + (size_t)gw * 128))[lane];
    float m = fmaxf(fabsf(v.x), fabsf(v.y));
#pragma unroll
    for (int d = 1; d < 64; d <<= 1) m = fmaxf(m, __shfl_xor(m, d));
    float inv = (m > 0.f) ? 32767.f / m : 0.f;
    int qa = __float2int_rn(v.x * inv);
    int qb = __float2int_rn(v.y * inv);
    uint packed = ((uint)qa & 0xFFFFu) | ((uint)qb << 16);
    ((uint*)xq)[(size_t)gw * 64 + lane] = packed;
    if (lane == 0) {
        float di = dinv[gw];
        meta[gw] = make_float2(di, di * (m * (1.f / 32767.f)));
    }
}

__device__ inline void unpackq(uint4 v, float f[8]) {
    f[0] = (float)(short)(v.x & 0xFFFFu);
    f[1] = (float)((int)v.x >> 16);
    f[2] = (float)(short)(v.y & 0xFFFFu);
    f[3] = (float)((int)v.y >> 16);
    f[4] = (float)(short)(v.z & 0xFFFFu);
    f[5] = (float)((int)v.z >> 16);
    f[6] = (float)(short)(v.w & 0xFFFFu);
    f[7] = (float)((int)v.w >> 16);
}

// Aggregation over int16 rows. One wave per node; quarter-wave (16 lanes)
// covers a 256B int16 row via uint4 -> 4 neighbor rows in flight/iteration.
// Gather weight per neighbor s = meta[s].y = dinv[s]*scale[s].
// WRITE_Q=1: re-quantize output to int16 (qout,mout) + svec = rowsum(A).
// WRITE_Q=0: write f32 rows to fout.
template <int WRITE_Q>
__launch_bounds__(256)
__global__ void k_aggq(const ushort* __restrict__ xq, const float2* __restrict__ meta,
                       float* __restrict__ fout,
                       ushort* __restrict__ qout, float2* __restrict__ mout,
                       float* __restrict__ svec,
                       const int* __restrict__ offs, const int* __restrict__ csr, int N) {
    int gw = (int)((blockIdx.x * (size_t)blockDim.x + threadIdx.x) >> 6);
    int lane = threadIdx.x & 63;
    if (gw >= N) return;
    int q = lane >> 4, ql = lane & 15;
    float2 ms = meta[gw];
    float di = ms.x;

    float acc[8];
#pragma unroll
    for (int j = 0; j < 8; ++j) acc[j] = 0.f;
    float ssum = (lane == 0) ? di : 0.f;

    if (q == 0) {  // self term: weight di*scale_self = ms.y
        uint4 v = *(const uint4*)(xq + (size_t)gw * 128 + ql * 8);
        float f[8];
        unpackq(v, f);
#pragma unroll
        for (int j = 0; j < 8; ++j) acc[j] = ms.y * f[j];
    }

    int s0 = offs[gw], s1 = offs[gw + 1];
    for (int base = s0; base < s1; base += 64) {
        int cnt = min(64, s1 - base);
        int sidx = 0;
        float wv = 0.f, dv = 0.f;   // lanes >= cnt keep 0 -> d==0 for padded t
        if (lane < cnt) {
            sidx = csr[base + lane];
            float2 mm = meta[sidx];
            dv = mm.x;
            wv = mm.y;
        }
        int iters = (cnt + 3) >> 2;
#pragma unroll 4
        for (int i = 0; i < iters; ++i) {
            int t = 4 * i + q;          // t <= 63 always
            // __shfl OUTSIDE any divergent guard: every source lane is active
            // and holds valid (possibly zero-padded) data.
            int s = __shfl(sidx, t);
            float d = __shfl(wv, t);
            float dd = 0.f;
            if (WRITE_Q) dd = __shfl(dv, t);   // compile-time uniform branch
            if (t < cnt) {
                uint4 v = *(const uint4*)(xq + (size_t)s * 128 + ql * 8);
                float f[8];
                unpackq(v, f);
#pragma unroll
                for (int j = 0; j < 8; ++j) acc[j] = fmaf(d, f[j], acc[j]);
                if (WRITE_Q && ql == 0) ssum += dd;
            }
        }
    }

    // butterfly combine: afterwards EVERY lane holds the full sum of its slice
#pragma unroll
    for (int j = 0; j < 8; ++j) {
        acc[j] += __shfl_xor(acc[j], 16);
        acc[j] += __shfl_xor(acc[j], 32);
        acc[j] *= di;
    }

    if (WRITE_Q) {
        ssum += __shfl_xor(ssum, 16);
        ssum += __shfl_xor(ssum, 32);
        if (lane == 0) svec[gw] = di * ssum;
        // row max over the 16 feature slices (all lanes have full slice sums)
        float m = 0.f;
#pragma unroll
        for (int j = 0; j < 8; ++j) m = fmaxf(m, fabsf(acc[j]));
#pragma unroll
        for (int d = 1; d < 16; d <<= 1) m = fmaxf(m, __shfl_xor(m, d));
        float inv = (m > 0.f) ? 32767.f / m : 0.f;
        if (q == 0) {
            uint4 o;
            int q0 = __float2int_rn(acc[0] * inv), q1 = __float2int_rn(acc[1] * inv);
            int q2 = __float2int_rn(acc[2] * inv), q3 = __float2int_rn(acc[3] * inv);
            int q4 = __float2int_rn(acc[4] * inv), q5 = __float2int_rn(acc[5] * inv);
            int q6 = __float2int_rn(acc[6] * inv), q7 = __float2int_rn(acc[7] * inv);
            o.x = ((uint)q0 & 0xFFFFu) | ((uint)q1 << 16);
            o.y = ((uint)q2 & 0xFFFFu) | ((uint)q3 << 16);
            o.z = ((uint)q4 & 0xFFFFu) | ((uint)q5 << 16);
            o.w = ((uint)q6 & 0xFFFFu) | ((uint)q7 << 16);
            *(uint4*)(qout + (size_t)gw * 128 + ql * 8) = o;
        }
        if (lane == 0) mout[gw] = make_float2(di, di * (m * (1.f / 32767.f)));
    } else {
        if (q == 0) {
            float4 o0, o1;
            o0.x = acc[0]; o0.y = acc[1]; o0.z = acc[2]; o0.w = acc[3];
            o1.x = acc[4]; o1.y = acc[5]; o1.z = acc[6]; o1.w = acc[7];
            *(float4*)(fout + (size_t)gw * 128 + ql * 8) = o0;
            *(float4*)(fout + (size_t)gw * 128 + ql * 8 + 4) = o1;
        }
    }
}

// W12 = W1 @ W2  (128x128 @ 128x128), one output per thread.
__global__ void k_w12(const float* __restrict__ W1, const float* __restrict__ W2,
                      float* __restrict__ w12) {
    int idx = blockIdx.x * 256 + threadIdx.x;  // 0..16383
    int i = idx >> 7, j = idx & 127;
    float s = 0.f;
#pragma unroll 8
    for (int k = 0; k < 128; ++k) s = fmaf(W1[i * 128 + k], W2[k * 128 + j], s);
    w12[idx] = s;
}

// cvec = b1^T @ W2  (128,)
__global__ void k_cvec(const float* __restrict__ b1, const float* __restrict__ W2,
                       float* __restrict__ cvec) {
    int j = threadIdx.x;
    float s = 0.f;
#pragma unroll 8
    for (int k = 0; k < 128; ++k) s = fmaf(b1[k], W2[k * 128 + j], s);
    cvec[j] = s;
}

// out = relu( X @ W12 + svec ⊗ cvec + b2 ) — fp32 vector GEMM, LDS-tiled.
// 512 threads / 128 rows per block: ws 64KB + xs 64KB = 128KB LDS ->
// 8 waves/CU (2 per SIMD) so LDS latency overlaps FMA (was 1 wave/SIMD,
// VALUBusy 32%). Inner loop k-step-4 with float4 a-reads (b128 only).
// Safe in-place (X == out): block stages its rows into LDS before writing.
__launch_bounds__(512)
__global__ void k_gemm(const float* __restrict__ X, const float* __restrict__ Wg,
                       const float* __restrict__ svec, const float* __restrict__ cvec,
                       const float* __restrict__ b2, float* __restrict__ out, int N) {
    __shared__ float ws[128 * 128];
    __shared__ float xs[128 * 128];
    int tid = threadIdx.x;
    int row0 = blockIdx.x * 128;

    // stage W12 (4096 float4, 8 iters x 512 threads)
    {
        const float4* srcv = (const float4*)Wg;
        float4* dstv = (float4*)ws;
#pragma unroll
        for (int it = 0; it < 8; ++it) dstv[it * 512 + tid] = srcv[it * 512 + tid];
    }
    // stage X rows [row0, row0+128), XOR-swizzled float4 groups
#pragma unroll
    for (int it = 0; it < 8; ++it) {
        int idx = it * 512 + tid;
        int r = idx >> 5, cg = idx & 31;
        int grow = row0 + r;
        float4 v = make_float4(0.f, 0.f, 0.f, 0.f);
        if (grow < N) v = *(const float4*)(X + (size_t)grow * 128 + cg * 4);
        int c0 = (cg * 4) ^ ((r & 7) << 2);
        *(float4*)&xs[r * 128 + c0] = v;
    }
    __syncthreads();

    int ty = tid >> 4, tx = tid & 15;  // 32 x 16 threads
    int r0 = ty * 4;                   // 4 rows per thread
    float acc0[4][4] = {{0.f}};        // cols 4tx..4tx+3
    float acc1[4][4] = {{0.f}};        // cols 64+4tx..+3

#pragma unroll 2
    for (int k0 = 0; k0 < 128; k0 += 4) {
        float4 w0[4], w1[4];
#pragma unroll
        for (int kk = 0; kk < 4; ++kk) {
            w0[kk] = *(const float4*)&ws[(k0 + kk) * 128 + 4 * tx];
            w1[kk] = *(const float4*)&ws[(k0 + kk) * 128 + 64 + 4 * tx];
        }
#pragma unroll
        for (int j = 0; j < 4; ++j) {
            int r = r0 + j;
            float4 a = *(const float4*)&xs[r * 128 + (k0 ^ ((r & 7) << 2))];
            float av[4] = {a.x, a.y, a.z, a.w};
#pragma unroll
            for (int kk = 0; kk < 4; ++kk) {
                acc0[j][0] = fmaf(av[kk], w0[kk].x, acc0[j][0]);
                acc0[j][1] = fmaf(av[kk], w0[kk].y, acc0[j][1]);
                acc0[j][2] = fmaf(av[kk], w0[kk].z, acc0[j][2]);
                acc0[j][3] = fmaf(av[kk], w0[kk].w, acc0[j][3]);
                acc1[j][0] = fmaf(av[kk], w1[kk].x, acc1[j][0]);
                acc1[j][1] = fmaf(av[kk], w1[kk].y, acc1[j][1]);
                acc1[j][2] = fmaf(av[kk], w1[kk].z, acc1[j][2]);
                acc1[j][3] = fmaf(av[kk], w1[kk].w, acc1[j][3]);
            }
        }
    }

    float c0v[4], c1v[4], b0v[4], b1v[4];
#pragma unroll
    for (int m = 0; m < 4; ++m) {
        c0v[m] = cvec[4 * tx + m];
        c1v[m] = cvec[64 + 4 * tx + m];
        b0v[m] = b2[4 * tx + m];
        b1v[m] = b2[64 + 4 * tx + m];
    }
#pragma unroll
    for (int j = 0; j < 4; ++j) {
        int grow = row0 + r0 + j;
        if (grow >= N) continue;
        float sv = svec[grow];
        float4 o0, o1;
        o0.x = fmaxf(acc0[j][0] + sv * c0v[0] + b0v[0], 0.f);
        o0.y = fmaxf(acc0[j][1] + sv * c0v[1] + b0v[1], 0.f);
        o0.z = fmaxf(acc0[j][2] + sv * c0v[2] + b0v[2], 0.f);
        o0.w = fmaxf(acc0[j][3] + sv * c0v[3] + b0v[3], 0.f);
        o1.x = fmaxf(acc1[j][0] + sv * c1v[0] + b1v[0], 0.f);
        o1.y = fmaxf(acc1[j][1] + sv * c1v[1] + b1v[1], 0.f);
        o1.z = fmaxf(acc1[j][2] + sv * c1v[2] + b1v[2], 0.f);
        o1.w = fmaxf(acc1[j][3] + sv * c1v[3] + b1v[3], 0.f);
        *(float4*)&out[(size_t)grow * 128 + 4 * tx] = o0;
        *(float4*)&out[(size_t)grow * 128 + 64 + 4 * tx] = o1;
    }
}

extern "C" void kernel_launch(void* const* d_in, const int* in_sizes, int n_in,
                              void* d_out, int out_size, void* d_ws, size_t ws_size,
                              hipStream_t stream) {
    const float* x  = (const float*)d_in[0];
    const int*   ei = (const int*)d_in[1];
    const float* W1 = (const float*)d_in[2];
    const float* b1 = (const float*)d_in[3];
    const float* W2 = (const float*)d_in[4];
    const float* b2 = (const float*)d_in[5];
    float* out = (float*)d_out;

    int N = in_sizes[0] / 128;
    int E = in_sizes[1] / 2;
    const int* srcE = ei;
    const int* dstE = ei + E;

    char* w = (char*)d_ws;
    size_t off = 0;
    auto alloc = [&](size_t bytes) {
        void* p = w + off;
        off = WS_ALIGN(off + bytes);
        return p;
    };
    ushort* xq   = (ushort*)alloc((size_t)N * 256);
    // union: rank (E*4) dead after k_fill; t1q written later by k_aggq<1>.
    void*  uni   = alloc((size_t)E * 4 > (size_t)N * 256 ? (size_t)E * 4 : (size_t)N * 256);
    int*   rank  = (int*)uni;
    ushort* t1q  = (ushort*)uni;
    int*   csr   = (int*)alloc((size_t)E * 4);
    float2* meta1 = (float2*)alloc((size_t)N * 8);
    float2* meta2 = (float2*)alloc((size_t)N * 8);
    int*   deg   = (int*)alloc((size_t)N * 4);
    int*   offs  = (int*)alloc((size_t)(N + 1) * 4);
    int*   bsums = (int*)alloc(4096);
    float* dinv  = (float*)alloc((size_t)N * 4);
    float* svec  = (float*)alloc((size_t)N * 4);
    float* w12   = (float*)alloc(128 * 128 * 4);
    float* cvec  = (float*)alloc(128 * 4);
    (void)ws_size; (void)n_in; (void)out_size;

    int nb = (N + 255) / 256;  // 391 for N=100000, fits k_scan2's 512
    int eb8 = (E + 8 * 256 - 1) / (8 * 256);

    k_init_deg<<<(N + 255) / 256, 256, 0, stream>>>(deg, N);
    k_rank<<<eb8, 256, 0, stream>>>(dstE, deg, rank, E, N);
    k_dinv<<<(N + 255) / 256, 256, 0, stream>>>(deg, dinv, N);
    k_scan1<<<nb, 256, 0, stream>>>(deg, offs, bsums, N);
    k_scan2<<<1, 512, 0, stream>>>(bsums, nb);
    k_scan3<<<nb, 256, 0, stream>>>(offs, bsums, N, E);
    k_fill<<<eb8, 256, 0, stream>>>(srcE, dstE, rank, offs, csr, E, N);
    // quantize x (rank is dead from here; t1q may overwrite it)
    k_toq16<<<(N + 3) / 4, 256, 0, stream>>>(x, dinv, xq, meta1, N);
    // pass 1: t1 = A x   (int16 in, int16 out) + svec = rowsum(A)
    k_aggq<1><<<(N + 3) / 4, 256, 0, stream>>>(xq, meta1, nullptr, t1q, meta2, svec,
                                               offs, csr, N);
    // pass 2: t2 = A t1  (int16 in, f32 out -> d_out as scratch)
    k_aggq<0><<<(N + 3) / 4, 256, 0, stream>>>(t1q, meta2, out, nullptr, nullptr, nullptr,
                                               offs, csr, N);
    k_w12<<<64, 256, 0, stream>>>(W1, W2, w12);
    k_cvec<<<1, 128, 0, stream>>>(b1, W2, cvec);
    // out = relu(t2 @ W12 + svec ⊗ cvec + b2), in-place on d_out
    k_gemm<<<(N + 127) / 128, 512, 0, stream>>>(out, w12, svec, cvec, b2, out, N);
}